// Round 2
// baseline (339.146 us; speedup 1.0000x reference)
//
#include <hip/hip_runtime.h>
#include <math.h>

// BEV deformable attention encoder, layer l = L-1 only.
// Round 2: CPB layer-2 as split-bf16 MFMA (3-term compensation ~ fp32 accuracy),
// register-tiled attention, fused offset-net, merged k/v conv.

#define NP 1600   // 40*40 query pixels
#define NJ 100    // 10*10 kv pixels

typedef __bf16 bf16x8 __attribute__((ext_vector_type(8)));
typedef float  f32x4  __attribute__((ext_vector_type(4)));
typedef float  f32x2  __attribute__((ext_vector_type(2)));
typedef int    i32x4  __attribute__((ext_vector_type(4)));

// ---------------- grouped 1x1 conv (q): 8 groups, cin/g=32, cout/g=64 ------
__global__ __launch_bounds__(256) void k_conv1x1(
    const float* __restrict__ x, const float* __restrict__ w,
    float* __restrict__ out, int P) {
  int b = blockIdx.x;
  int g = b >> 3;
  int co0 = g * 64 + (b & 7) * 8;
  const float* xg = x + g * 32 * P;
  const float* wr = w + co0 * 32;   // uniform -> scalar loads
  for (int p = threadIdx.x; p < P; p += 256) {
    float acc[8];
#pragma unroll
    for (int o = 0; o < 8; ++o) acc[o] = 0.f;
#pragma unroll
    for (int ci = 0; ci < 32; ++ci) {
      float xv = xg[ci * P + p];
#pragma unroll
      for (int o = 0; o < 8; ++o) acc[o] = fmaf(wr[o * 32 + ci], xv, acc[o]);
    }
#pragma unroll
    for (int o = 0; o < 8; ++o) out[(co0 + o) * P + p] = acc[o];
  }
}

// ------- fused offset net: dw 6x6 s4 + GELU -> 1x1 -> tanh*4 -> grid/samp ---
// One block per group g. Produces gkv (normalized grid) and bilinear sampling
// weights/indices (consumed by k_convkv).
__global__ __launch_bounds__(256) void k_offnet(
    const float* __restrict__ q, const float* __restrict__ w1,
    const float* __restrict__ b1, const float* __restrict__ w2,
    float* __restrict__ gkv, float* __restrict__ samp_w,
    int* __restrict__ samp_i) {
  __shared__ float off_lds[64][100];
  int g = blockIdx.x;
  int t = threadIdx.x;
  for (int idx = t; idx < 6400; idx += 256) {
    int d = idx / 100, j = idx - (idx / 100) * 100;
    int oy = j / 10, ox = j - (j / 10) * 10;
    float acc = b1[d];
    const float* qc = q + (g * 64 + d) * NP;
#pragma unroll
    for (int ky = 0; ky < 6; ++ky) {
      int iy = oy * 4 - 1 + ky;
      if (iy < 0 || iy >= 40) continue;
#pragma unroll
      for (int kx = 0; kx < 6; ++kx) {
        int ix = ox * 4 - 1 + kx;
        if (ix < 0 || ix >= 40) continue;
        acc = fmaf(w1[d * 36 + ky * 6 + kx], qc[iy * 40 + ix], acc);
      }
    }
    off_lds[d][j] = 0.5f * acc * (1.0f + erff(acc * 0.70710678118654752440f));
  }
  __syncthreads();
  if (t < 100) {
    float ax = 0.f, ay = 0.f;
#pragma unroll 16
    for (int c = 0; c < 64; ++c) {
      float o = off_lds[c][t];
      ax = fmaf(w2[c], o, ax);
      ay = fmaf(w2[64 + c], o, ay);
    }
    ax = tanhf(ax) * 4.f;
    ay = tanhf(ay) * 4.f;
    float vx = (float)(t % 10) + ax;
    float vy = (float)(t / 10) + ay;
    float g0 = 2.f * vx / 9.f - 1.f;
    float g1 = 2.f * vy / 9.f - 1.f;
    gkv[(g * 100 + t) * 2 + 0] = g0;
    gkv[(g * 100 + t) * 2 + 1] = g1;
    float gx = ((g0 + 1.f) * 40.f - 1.f) * 0.5f;
    float gy = ((g1 + 1.f) * 40.f - 1.f) * 0.5f;
    float x0f = floorf(gx), y0f = floorf(gy);
    float wx = gx - x0f, wy = gy - y0f;
    bool mx0 = (x0f >= 0.f) && (x0f <= 39.f);
    bool mx1 = (x0f + 1.f >= 0.f) && (x0f + 1.f <= 39.f);
    bool my0 = (y0f >= 0.f) && (y0f <= 39.f);
    bool my1 = (y0f + 1.f >= 0.f) && (y0f + 1.f <= 39.f);
    int ix0 = (int)fminf(fmaxf(x0f, 0.f), 39.f);
    int ix1 = (int)fminf(fmaxf(x0f + 1.f, 0.f), 39.f);
    int iy0 = (int)fminf(fmaxf(y0f, 0.f), 39.f);
    int iy1 = (int)fminf(fmaxf(y0f + 1.f, 0.f), 39.f);
    f32x4 wv4;
    wv4[0] = (1.f - wx) * (1.f - wy) * ((mx0 && my0) ? 1.f : 0.f);
    wv4[1] = wx * (1.f - wy) * ((mx1 && my0) ? 1.f : 0.f);
    wv4[2] = (1.f - wx) * wy * ((mx0 && my1) ? 1.f : 0.f);
    wv4[3] = wx * wy * ((mx1 && my1) ? 1.f : 0.f);
    i32x4 iv4;
    iv4[0] = iy0 * 40 + ix0; iv4[1] = iy0 * 40 + ix1;
    iv4[2] = iy1 * 40 + ix0; iv4[3] = iy1 * 40 + ix1;
    *(f32x4*)(samp_w + (g * 100 + t) * 4) = wv4;
    *(i32x4*)(samp_i + (g * 100 + t) * 4) = iv4;
  }
}

// ------- k & v grouped conv in one launch, inline grid-sample into LDS ------
__global__ __launch_bounds__(256) void k_convkv(
    const float* __restrict__ x, const float* __restrict__ wk,
    const float* __restrict__ wv, const float* __restrict__ samp_w,
    const int* __restrict__ samp_i, float* __restrict__ kout,
    float* __restrict__ vout) {
  __shared__ float kv_lds[32][100];
  int b = blockIdx.x;
  int side = b >> 6;
  int bb = b & 63;
  int g = bb >> 3;
  int co0 = g * 64 + (bb & 7) * 8;
  const float* w = (side ? wv : wk) + co0 * 32;
  float* outp = side ? vout : kout;
  const float* xg = x + g * 32 * NP;
  int t = threadIdx.x;
  for (int idx = t; idx < 3200; idx += 256) {
    int c = idx / 100, j = idx - (idx / 100) * 100;
    f32x4 sw = *(const f32x4*)(samp_w + (g * 100 + j) * 4);
    i32x4 si = *(const i32x4*)(samp_i + (g * 100 + j) * 4);
    const float* xc = xg + c * NP;
    kv_lds[c][j] = sw[0] * xc[si[0]] + sw[1] * xc[si[1]]
                 + sw[2] * xc[si[2]] + sw[3] * xc[si[3]];
  }
  __syncthreads();
  for (int idx = t; idx < 800; idx += 256) {
    int o = idx / 100, j = idx - (idx / 100) * 100;
    float acc = 0.f;
#pragma unroll
    for (int ci = 0; ci < 32; ++ci)
      acc = fmaf(w[o * 32 + ci], kv_lds[ci][j], acc);
    outp[(co0 + o) * 100 + j] = acc;
  }
}

// ---------------- CPB bias MLP via split-bf16 MFMA -------------------------
// layer1 (2->64, relu) in fp32 VALU; layer2 (64->64) as 16x16x32 bf16 MFMA
// with 3-term compensation (hi*hi + hi*lo + lo*hi ~ fp32); epilogue relu+w2.
// Tile = 16 pairs; 80000 tiles; one tile per wave-iteration.
__global__ __launch_bounds__(256) void k_cpb_mfma(
    const float* __restrict__ gkv,
    const float* __restrict__ w0, const float* __restrict__ b0,
    const float* __restrict__ w1, const float* __restrict__ b1v,
    const float* __restrict__ w2, const float* __restrict__ b2,
    float* __restrict__ bias) {
  int lane = threadIdx.x & 63;
  int gw = blockIdx.x * 4 + (threadIdx.x >> 6);   // global wave id (5000 total)
  int nw = gridDim.x * 4;
  int row = lane & 15;       // A-row / B-col / C-col
  int kgrp = lane >> 4;      // k-group 0..3

  // B fragments: B[k][n] = w1[n][k]; frag(ct,s): k = s*32+kgrp*8+e, n = ct*16+row
  bf16x8 Bhi[4][2], Blo[4][2];
#pragma unroll
  for (int ct = 0; ct < 4; ++ct)
#pragma unroll
    for (int s = 0; s < 2; ++s)
#pragma unroll
      for (int e = 0; e < 8; ++e) {
        float wvv = w1[(ct * 16 + row) * 64 + s * 32 + kgrp * 8 + e];
        __bf16 h = (__bf16)wvv;
        Bhi[ct][s][e] = h;
        Blo[ct][s][e] = (__bf16)(wvv - (float)h);
      }
  // layer-1 weights for this lane's k-slots
  float w0x[2][8], w0y[2][8], b0v[2][8];
#pragma unroll
  for (int s = 0; s < 2; ++s)
#pragma unroll
    for (int e = 0; e < 8; ++e) {
      int kk = s * 32 + kgrp * 8 + e;
      w0x[s][e] = w0[2 * kk];
      w0y[s][e] = w0[2 * kk + 1];
      b0v[s][e] = b0[kk];
    }
  float b1c[4], w2c[4];
#pragma unroll
  for (int ct = 0; ct < 4; ++ct) {
    b1c[ct] = b1v[ct * 16 + row];
    w2c[ct] = w2[ct * 16 + row];
  }
  float bb = b2[0];

  for (int t = gw; t < 80000; t += nw) {
    int p = t * 16 + row;
    int g = p / 160000;
    int r2 = p - g * 160000;
    int i = r2 / 100;
    int j = r2 - i * 100;
    int iy = i / 40;
    int ix = i - iy * 40;
    float qx = (float)ix * (2.f / 39.f) - 1.f;
    float qy = (float)iy * (2.f / 39.f) - 1.f;
    const float* gp = gkv + (g * 100 + j) * 2;
    float u = qx - gp[0];
    float vv = qy - gp[1];
    float su = copysignf(log1pf(fabsf(u)), u);
    float sv = copysignf(log1pf(fabsf(vv)), vv);

    f32x4 acc[4];
#pragma unroll
    for (int ct = 0; ct < 4; ++ct) {
      acc[ct][0] = 0.f; acc[ct][1] = 0.f; acc[ct][2] = 0.f; acc[ct][3] = 0.f;
    }
#pragma unroll
    for (int s = 0; s < 2; ++s) {
      bf16x8 Ahi, Alo;
#pragma unroll
      for (int e = 0; e < 8; ++e) {
        float h0 = fmaf(w0x[s][e], su, fmaf(w0y[s][e], sv, b0v[s][e]));
        h0 = fmaxf(h0, 0.f);
        __bf16 hh = (__bf16)h0;
        Ahi[e] = hh;
        Alo[e] = (__bf16)(h0 - (float)hh);
      }
#pragma unroll
      for (int ct = 0; ct < 4; ++ct) {
        acc[ct] = __builtin_amdgcn_mfma_f32_16x16x32_bf16(Ahi, Bhi[ct][s], acc[ct], 0, 0, 0);
        acc[ct] = __builtin_amdgcn_mfma_f32_16x16x32_bf16(Ahi, Blo[ct][s], acc[ct], 0, 0, 0);
        acc[ct] = __builtin_amdgcn_mfma_f32_16x16x32_bf16(Alo, Bhi[ct][s], acc[ct], 0, 0, 0);
      }
    }
    // epilogue: s2[c] = acc + b1; bias_row = sum_c w2[c]*relu(s2[c]) + b2
    float part[4];
#pragma unroll
    for (int ri = 0; ri < 4; ++ri) {
      float s2 = 0.f;
#pragma unroll
      for (int ct = 0; ct < 4; ++ct) {
        float val = acc[ct][ri] + b1c[ct];
        s2 = fmaf(w2c[ct], fmaxf(val, 0.f), s2);
      }
      part[ri] = s2;
    }
#pragma unroll
    for (int m = 1; m < 16; m <<= 1) {
#pragma unroll
      for (int ri = 0; ri < 4; ++ri) part[ri] += __shfl_xor(part[ri], m);
    }
    if (row == 0) {
      f32x4 o;
      o[0] = part[0] + bb; o[1] = part[1] + bb;
      o[2] = part[2] + bb; o[3] = part[3] + bb;
      *(f32x4*)(bias + t * 16 + kgrp * 4) = o;
    }
  }
}

// ---------------- fused attention, register-tiled --------------------------
__global__ __launch_bounds__(256) void k_attn(
    const float* __restrict__ q, const float* __restrict__ k,
    const float* __restrict__ v, const float* __restrict__ bias,
    float* __restrict__ inner) {
  __shared__ float k_lds[64][104];   // [d][j], rows 16B-aligned
  __shared__ float v_lds[100][68];   // [j][d], rows 16B-aligned
  __shared__ float q_lds[64][36];    // [d][i], rows 16B-aligned
  __shared__ float s_lds[32][100];
  int h = blockIdx.x / 50;
  int i0 = (blockIdx.x % 50) * 32;
  int t = threadIdx.x;
  for (int idx = t; idx < 6400; idx += 256) {
    int d = idx / 100, j = idx - (idx / 100) * 100;
    float kvv = k[(h * 64 + d) * 100 + j];
    k_lds[d][j] = kvv;
    v_lds[j][d] = v[(h * 64 + d) * 100 + j];
  }
  for (int idx = t; idx < 2048; idx += 256) {
    int d = idx >> 5, i = idx & 31;
    q_lds[d][i] = q[(h * 64 + d) * NP + i0 + i] * 0.125f;
  }
  __syncthreads();
  // sim: 4x4 register tiles, float4 LDS reads (8 i-tiles x 25 j-tiles = 200)
  if (t < 200) {
    int ib = (t / 25) * 4, jb = (t % 25) * 4;
    float a[4][4];
#pragma unroll
    for (int ii = 0; ii < 4; ++ii)
#pragma unroll
      for (int jj = 0; jj < 4; ++jj) a[ii][jj] = 0.f;
    for (int d = 0; d < 64; ++d) {
      f32x4 qv = *(const f32x4*)&q_lds[d][ib];
      f32x4 kv4 = *(const f32x4*)&k_lds[d][jb];
#pragma unroll
      for (int ii = 0; ii < 4; ++ii)
#pragma unroll
        for (int jj = 0; jj < 4; ++jj)
          a[ii][jj] = fmaf(qv[ii], kv4[jj], a[ii][jj]);
    }
    const float* brow = bias + (h * 1600 + i0) * 100;
#pragma unroll
    for (int ii = 0; ii < 4; ++ii)
#pragma unroll
      for (int jj = 0; jj < 4; ++jj)
        s_lds[ib + ii][jb + jj] = a[ii][jj] + brow[(ib + ii) * 100 + jb + jj];
  }
  __syncthreads();
  // softmax over j: 8 lanes per row
  {
    int i = t >> 3, sub = t & 7;
    float m = -1e30f;
    for (int j = sub; j < 100; j += 8) m = fmaxf(m, s_lds[i][j]);
#pragma unroll
    for (int off = 1; off < 8; off <<= 1) m = fmaxf(m, __shfl_xor(m, off));
    float sum = 0.f;
    for (int j = sub; j < 100; j += 8) {
      float e = expf(s_lds[i][j] - m);
      s_lds[i][j] = e;
      sum += e;
    }
#pragma unroll
    for (int off = 1; off < 8; off <<= 1) sum += __shfl_xor(sum, off);
    float inv = 1.f / sum;
    for (int j = sub; j < 100; j += 8) s_lds[i][j] *= inv;
  }
  __syncthreads();
  // PV: 2i x 4d register tiles (16 x 16 = 256 thread-tiles)
  {
    int ib = (t >> 4) * 2, db = (t & 15) * 4;
    float a0[4], a1[4];
#pragma unroll
    for (int dd = 0; dd < 4; ++dd) { a0[dd] = 0.f; a1[dd] = 0.f; }
    for (int j = 0; j < 100; ++j) {
      f32x4 vv = *(const f32x4*)&v_lds[j][db];
      float s0 = s_lds[ib][j], s1 = s_lds[ib + 1][j];
#pragma unroll
      for (int dd = 0; dd < 4; ++dd) {
        a0[dd] = fmaf(s0, vv[dd], a0[dd]);
        a1[dd] = fmaf(s1, vv[dd], a1[dd]);
      }
    }
#pragma unroll
    for (int dd = 0; dd < 4; ++dd) {
      f32x2 o; o[0] = a0[dd]; o[1] = a1[dd];
      *(f32x2*)&inner[(h * 64 + db + dd) * NP + i0 + ib] = o;
    }
  }
}

// ---------------- output projection 256x512 @ 512x1600 + bias --------------
__global__ __launch_bounds__(256) void k_proj(
    const float* __restrict__ inner, const float* __restrict__ w,
    const float* __restrict__ bo, float* __restrict__ out) {
  int o0 = (blockIdx.x & 63) * 4;
  int p0 = (blockIdx.x >> 6) * 320;
  const float* w0r = w + o0 * 512;
  for (int p = p0 + threadIdx.x; p < p0 + 320; p += 256) {
    float a0 = 0.f, a1 = 0.f, a2 = 0.f, a3 = 0.f;
#pragma unroll 8
    for (int c = 0; c < 512; ++c) {
      float xv = inner[c * NP + p];
      a0 = fmaf(w0r[c], xv, a0);
      a1 = fmaf(w0r[512 + c], xv, a1);
      a2 = fmaf(w0r[1024 + c], xv, a2);
      a3 = fmaf(w0r[1536 + c], xv, a3);
    }
    out[(o0 + 0) * NP + p] = a0 + bo[o0 + 0];
    out[(o0 + 1) * NP + p] = a1 + bo[o0 + 1];
    out[(o0 + 2) * NP + p] = a2 + bo[o0 + 2];
    out[(o0 + 3) * NP + p] = a3 + bo[o0 + 3];
  }
}

extern "C" void kernel_launch(void* const* d_in, const int* in_sizes, int n_in,
                              void* d_out, int out_size, void* d_ws, size_t ws_size,
                              hipStream_t stream) {
  int L = in_sizes[1] / (512 * 32);
  int l = L - 1;
  const float* x      = (const float*)d_in[0];
  const float* wq     = (const float*)d_in[1]  + (size_t)l * 512 * 32;
  const float* wk     = (const float*)d_in[2]  + (size_t)l * 512 * 32;
  const float* wv     = (const float*)d_in[3]  + (size_t)l * 512 * 32;
  const float* w_off1 = (const float*)d_in[4]  + (size_t)l * 64 * 36;
  const float* b_off1 = (const float*)d_in[5]  + (size_t)l * 64;
  const float* w_off2 = (const float*)d_in[6]  + (size_t)l * 2 * 64;
  const float* cpb_w0 = (const float*)d_in[7]  + (size_t)l * 64 * 2;
  const float* cpb_b0 = (const float*)d_in[8]  + (size_t)l * 64;
  const float* cpb_w1 = (const float*)d_in[9]  + (size_t)l * 64 * 64;
  const float* cpb_b1 = (const float*)d_in[10] + (size_t)l * 64;
  const float* cpb_w2 = (const float*)d_in[11] + (size_t)l * 64;
  const float* cpb_b2 = (const float*)d_in[12] + (size_t)l * 1;
  const float* w_out  = (const float*)d_in[13] + (size_t)l * 256 * 512;
  const float* b_out  = (const float*)d_in[14] + (size_t)l * 256;
  float* out = (float*)d_out;

  float* ws = (float*)d_ws;
  float* q_ws    = ws;                    // 819200
  float* gkv     = ws + 819200;           // 1600
  float* samp_w  = ws + 820800;           // 3200
  int*   samp_i  = (int*)(ws + 824000);   // 3200
  float* k_ws    = ws + 827200;           // 51200
  float* v_ws    = ws + 878400;           // 51200
  float* bias_ws = ws + 929600;           // 1280000
  float* inner   = ws + 2209600;          // 819200  (end: 3,028,800 f = 12.1 MB)

  k_conv1x1<<<64, 256, 0, stream>>>(x, wq, q_ws, NP);
  k_offnet<<<8, 256, 0, stream>>>(q_ws, w_off1, b_off1, w_off2,
                                  gkv, samp_w, samp_i);
  k_convkv<<<128, 256, 0, stream>>>(x, wk, wv, samp_w, samp_i, k_ws, v_ws);
  k_cpb_mfma<<<1250, 256, 0, stream>>>(gkv, cpb_w0, cpb_b0, cpb_w1, cpb_b1,
                                       cpb_w2, cpb_b2, bias_ws);
  k_attn<<<400, 256, 0, stream>>>(q_ws, k_ws, v_ws, bias_ws, inner);
  k_proj<<<320, 256, 0, stream>>>(inner, w_out, b_out, out);
}

// Round 3
// 174.182 us; speedup vs baseline: 1.9471x; 1.9471x over previous
//
#include <hip/hip_runtime.h>
#include <math.h>

// BEV deformable attention encoder, layer l = L-1 only.
// Round 3: occupancy pass. Offset net re-parallelized (dw 200 blocks; pw+sample
// +k/v-conv fused into one wave per (g,j)); proj 800x64 with 8-deep ILP;
// q-conv p-split. cpb MFMA and attn unchanged.

#define NP 1600   // 40*40 query pixels
#define NJ 100    // 10*10 kv pixels

typedef __bf16 bf16x8 __attribute__((ext_vector_type(8)));
typedef float  f32x4  __attribute__((ext_vector_type(4)));
typedef float  f32x2  __attribute__((ext_vector_type(2)));

// ---------------- grouped 1x1 conv (q): 8 groups, cin/g=32, cout/g=64 ------
// grid 320: b -> g (8) x oc-chunk (8) x p-tile (5 of 320)
__global__ __launch_bounds__(256) void k_conv1x1(
    const float* __restrict__ x, const float* __restrict__ w,
    float* __restrict__ out) {
  int b = blockIdx.x;
  int g = b / 40;
  int r = b - g * 40;
  int oc = r / 5;
  int p0 = (r - oc * 5) * 320;
  int co0 = g * 64 + oc * 8;
  const float* xg = x + g * 32 * NP;
  const float* wr = w + co0 * 32;   // block-uniform -> scalar loads
  for (int p = p0 + threadIdx.x; p < p0 + 320; p += 256) {
    float acc[8];
#pragma unroll
    for (int o = 0; o < 8; ++o) acc[o] = 0.f;
#pragma unroll
    for (int ci = 0; ci < 32; ++ci) {
      float xv = xg[ci * NP + p];
#pragma unroll
      for (int o = 0; o < 8; ++o) acc[o] = fmaf(wr[o * 32 + ci], xv, acc[o]);
    }
#pragma unroll
    for (int o = 0; o < 8; ++o) out[(co0 + o) * NP + p] = acc[o];
  }
}

// ------------- offset depthwise 6x6 s4 pad1 + bias + exact GELU ------------
// 200 blocks x 256, one output element per thread. off1 layout [g][d][j].
__global__ __launch_bounds__(256) void k_off_dw(
    const float* __restrict__ q, const float* __restrict__ w1,
    const float* __restrict__ b1, float* __restrict__ off1) {
  int idx = blockIdx.x * 256 + threadIdx.x;   // 51200 exactly
  int j = idx % 100;
  int d = (idx / 100) & 63;
  int bg = idx / 6400;
  int oy = j / 10, ox = j - (j / 10) * 10;
  float acc = b1[d];
  const float* qc = q + (bg * 64 + d) * NP;
#pragma unroll
  for (int ky = 0; ky < 6; ++ky) {
    int iy = oy * 4 - 1 + ky;
    if (iy < 0 || iy >= 40) continue;
#pragma unroll
    for (int kx = 0; kx < 6; ++kx) {
      int ix = ox * 4 - 1 + kx;
      if (ix < 0 || ix >= 40) continue;
      acc = fmaf(w1[d * 36 + ky * 6 + kx], qc[iy * 40 + ix], acc);
    }
  }
  off1[idx] = 0.5f * acc * (1.0f + erff(acc * 0.70710678118654752440f));
}

// ------- fused: offset 1x1 + tanh*4 + grid + bilinear sample + k/v conv ----
// One WAVE per (g,j): 800 waves = 200 blocks x 256.
// lane = c for the 64-c dot; butterfly reduce; lanes 0-31 gather 4 taps;
// shfl-broadcast drives both grouped convs (lane = cout).
__global__ __launch_bounds__(256) void k_off_pw_kv(
    const float* __restrict__ off1, const float* __restrict__ w2,
    const float* __restrict__ x, const float* __restrict__ wk,
    const float* __restrict__ wv, float* __restrict__ gkv,
    float* __restrict__ kout, float* __restrict__ vout) {
  int lane = threadIdx.x & 63;
  int wid = blockIdx.x * 4 + (threadIdx.x >> 6);
  int g = wid / 100;
  int j = wid - g * 100;
  // preload this lane's conv weight rows (k and v): 32 floats each
  const float* wkr = wk + (g * 64 + lane) * 32;
  const float* wvr = wv + (g * 64 + lane) * 32;
  float wkreg[32], wvreg[32];
#pragma unroll
  for (int q4 = 0; q4 < 8; ++q4) {
    f32x4 a = *(const f32x4*)(wkr + q4 * 4);
    f32x4 b = *(const f32x4*)(wvr + q4 * 4);
#pragma unroll
    for (int e = 0; e < 4; ++e) { wkreg[q4 * 4 + e] = a[e]; wvreg[q4 * 4 + e] = b[e]; }
  }
  // pointwise offset conv: ax = sum_c w2[0][c]*o, ay = sum_c w2[1][c]*o
  float o = off1[(g * 64 + lane) * 100 + j];
  float px = w2[lane] * o, py = w2[64 + lane] * o;
#pragma unroll
  for (int m = 1; m < 64; m <<= 1) {
    px += __shfl_xor(px, m);
    py += __shfl_xor(py, m);
  }
  float ax = tanhf(px) * 4.f;
  float ay = tanhf(py) * 4.f;
  float vx = (float)(j - (j / 10) * 10) + ax;
  float vy = (float)(j / 10) + ay;
  float g0 = 2.f * vx / 9.f - 1.f;
  float g1 = 2.f * vy / 9.f - 1.f;
  if (lane == 0) {
    f32x2 gv; gv[0] = g0; gv[1] = g1;
    *(f32x2*)(gkv + (g * 100 + j) * 2) = gv;
  }
  // bilinear sample (all lanes compute the uniform weights; lanes<32 gather)
  float gx = ((g0 + 1.f) * 40.f - 1.f) * 0.5f;
  float gy = ((g1 + 1.f) * 40.f - 1.f) * 0.5f;
  float x0f = floorf(gx), y0f = floorf(gy);
  float wx = gx - x0f, wy = gy - y0f;
  bool mx0 = (x0f >= 0.f) && (x0f <= 39.f);
  bool mx1 = (x0f + 1.f >= 0.f) && (x0f + 1.f <= 39.f);
  bool my0 = (y0f >= 0.f) && (y0f <= 39.f);
  bool my1 = (y0f + 1.f >= 0.f) && (y0f + 1.f <= 39.f);
  int ix0 = (int)fminf(fmaxf(x0f, 0.f), 39.f);
  int ix1 = (int)fminf(fmaxf(x0f + 1.f, 0.f), 39.f);
  int iy0 = (int)fminf(fmaxf(y0f, 0.f), 39.f);
  int iy1 = (int)fminf(fmaxf(y0f + 1.f, 0.f), 39.f);
  float w00 = (1.f - wx) * (1.f - wy) * ((mx0 && my0) ? 1.f : 0.f);
  float w10 = wx * (1.f - wy) * ((mx1 && my0) ? 1.f : 0.f);
  float w01 = (1.f - wx) * wy * ((mx0 && my1) ? 1.f : 0.f);
  float w11 = wx * wy * ((mx1 && my1) ? 1.f : 0.f);
  int b00 = iy0 * 40 + ix0, b10 = iy0 * 40 + ix1;
  int b01 = iy1 * 40 + ix0, b11 = iy1 * 40 + ix1;
  float kvc = 0.f;
  if (lane < 32) {
    const float* xc = x + (g * 32 + lane) * NP;
    kvc = w00 * xc[b00] + w10 * xc[b10] + w01 * xc[b01] + w11 * xc[b11];
  }
  // grouped k/v conv: lane = cout, broadcast kv channel values
  float kacc = 0.f, vacc = 0.f;
#pragma unroll
  for (int c = 0; c < 32; ++c) {
    float kvb = __shfl(kvc, c);
    kacc = fmaf(wkreg[c], kvb, kacc);
    vacc = fmaf(wvreg[c], kvb, vacc);
  }
  kout[(g * 64 + lane) * 100 + j] = kacc;
  vout[(g * 64 + lane) * 100 + j] = vacc;
}

// ---------------- CPB bias MLP via split-bf16 MFMA -------------------------
__global__ __launch_bounds__(256) void k_cpb_mfma(
    const float* __restrict__ gkv,
    const float* __restrict__ w0, const float* __restrict__ b0,
    const float* __restrict__ w1, const float* __restrict__ b1v,
    const float* __restrict__ w2, const float* __restrict__ b2,
    float* __restrict__ bias) {
  int lane = threadIdx.x & 63;
  int gw = blockIdx.x * 4 + (threadIdx.x >> 6);   // 5000 waves
  int nw = gridDim.x * 4;
  int row = lane & 15;
  int kgrp = lane >> 4;

  bf16x8 Bhi[4][2], Blo[4][2];
#pragma unroll
  for (int ct = 0; ct < 4; ++ct)
#pragma unroll
    for (int s = 0; s < 2; ++s)
#pragma unroll
      for (int e = 0; e < 8; ++e) {
        float wvv = w1[(ct * 16 + row) * 64 + s * 32 + kgrp * 8 + e];
        __bf16 h = (__bf16)wvv;
        Bhi[ct][s][e] = h;
        Blo[ct][s][e] = (__bf16)(wvv - (float)h);
      }
  float w0x[2][8], w0y[2][8], b0v[2][8];
#pragma unroll
  for (int s = 0; s < 2; ++s)
#pragma unroll
    for (int e = 0; e < 8; ++e) {
      int kk = s * 32 + kgrp * 8 + e;
      w0x[s][e] = w0[2 * kk];
      w0y[s][e] = w0[2 * kk + 1];
      b0v[s][e] = b0[kk];
    }
  float b1c[4], w2c[4];
#pragma unroll
  for (int ct = 0; ct < 4; ++ct) {
    b1c[ct] = b1v[ct * 16 + row];
    w2c[ct] = w2[ct * 16 + row];
  }
  float bb = b2[0];

  for (int t = gw; t < 80000; t += nw) {
    // g is tile-uniform: p = 16t+row, 160000 = 16*10000
    int g = t / 10000;
    int tr = t - g * 10000;
    int r2 = 16 * tr + row;
    int i = r2 / 100;
    int j = r2 - i * 100;
    int iy = i / 40;
    int ix = i - iy * 40;
    float qx = (float)ix * (2.f / 39.f) - 1.f;
    float qy = (float)iy * (2.f / 39.f) - 1.f;
    const float* gp = gkv + (g * 100 + j) * 2;
    float u = qx - gp[0];
    float vv = qy - gp[1];
    float su = copysignf(log1pf(fabsf(u)), u);
    float sv = copysignf(log1pf(fabsf(vv)), vv);

    f32x4 acc[4];
#pragma unroll
    for (int ct = 0; ct < 4; ++ct) {
      acc[ct][0] = 0.f; acc[ct][1] = 0.f; acc[ct][2] = 0.f; acc[ct][3] = 0.f;
    }
#pragma unroll
    for (int s = 0; s < 2; ++s) {
      bf16x8 Ahi, Alo;
#pragma unroll
      for (int e = 0; e < 8; ++e) {
        float h0 = fmaf(w0x[s][e], su, fmaf(w0y[s][e], sv, b0v[s][e]));
        h0 = fmaxf(h0, 0.f);
        __bf16 hh = (__bf16)h0;
        Ahi[e] = hh;
        Alo[e] = (__bf16)(h0 - (float)hh);
      }
#pragma unroll
      for (int ct = 0; ct < 4; ++ct) {
        acc[ct] = __builtin_amdgcn_mfma_f32_16x16x32_bf16(Ahi, Bhi[ct][s], acc[ct], 0, 0, 0);
        acc[ct] = __builtin_amdgcn_mfma_f32_16x16x32_bf16(Ahi, Blo[ct][s], acc[ct], 0, 0, 0);
        acc[ct] = __builtin_amdgcn_mfma_f32_16x16x32_bf16(Alo, Bhi[ct][s], acc[ct], 0, 0, 0);
      }
    }
    float part[4];
#pragma unroll
    for (int ri = 0; ri < 4; ++ri) {
      float s2 = 0.f;
#pragma unroll
      for (int ct = 0; ct < 4; ++ct) {
        float val = acc[ct][ri] + b1c[ct];
        s2 = fmaf(w2c[ct], fmaxf(val, 0.f), s2);
      }
      part[ri] = s2;
    }
#pragma unroll
    for (int m = 1; m < 16; m <<= 1) {
#pragma unroll
      for (int ri = 0; ri < 4; ++ri) part[ri] += __shfl_xor(part[ri], m);
    }
    if (row == 0) {
      f32x4 o;
      o[0] = part[0] + bb; o[1] = part[1] + bb;
      o[2] = part[2] + bb; o[3] = part[3] + bb;
      *(f32x4*)(bias + t * 16 + kgrp * 4) = o;
    }
  }
}

// ---------------- fused attention, register-tiled --------------------------
__global__ __launch_bounds__(256) void k_attn(
    const float* __restrict__ q, const float* __restrict__ k,
    const float* __restrict__ v, const float* __restrict__ bias,
    float* __restrict__ inner) {
  __shared__ float k_lds[64][104];
  __shared__ float v_lds[100][68];
  __shared__ float q_lds[64][36];
  __shared__ float s_lds[32][100];
  int h = blockIdx.x / 50;
  int i0 = (blockIdx.x % 50) * 32;
  int t = threadIdx.x;
  for (int idx = t; idx < 6400; idx += 256) {
    int d = idx / 100, j = idx - (idx / 100) * 100;
    k_lds[d][j] = k[(h * 64 + d) * 100 + j];
    v_lds[j][d] = v[(h * 64 + d) * 100 + j];
  }
  for (int idx = t; idx < 2048; idx += 256) {
    int d = idx >> 5, i = idx & 31;
    q_lds[d][i] = q[(h * 64 + d) * NP + i0 + i] * 0.125f;
  }
  __syncthreads();
  if (t < 200) {
    int ib = (t / 25) * 4, jb = (t % 25) * 4;
    float a[4][4];
#pragma unroll
    for (int ii = 0; ii < 4; ++ii)
#pragma unroll
      for (int jj = 0; jj < 4; ++jj) a[ii][jj] = 0.f;
    for (int d = 0; d < 64; ++d) {
      f32x4 qv = *(const f32x4*)&q_lds[d][ib];
      f32x4 kv4 = *(const f32x4*)&k_lds[d][jb];
#pragma unroll
      for (int ii = 0; ii < 4; ++ii)
#pragma unroll
        for (int jj = 0; jj < 4; ++jj)
          a[ii][jj] = fmaf(qv[ii], kv4[jj], a[ii][jj]);
    }
    const float* brow = bias + (h * 1600 + i0) * 100;
#pragma unroll
    for (int ii = 0; ii < 4; ++ii)
#pragma unroll
      for (int jj = 0; jj < 4; ++jj)
        s_lds[ib + ii][jb + jj] = a[ii][jj] + brow[(ib + ii) * 100 + jb + jj];
  }
  __syncthreads();
  {
    int i = t >> 3, sub = t & 7;
    float m = -1e30f;
    for (int j = sub; j < 100; j += 8) m = fmaxf(m, s_lds[i][j]);
#pragma unroll
    for (int off = 1; off < 8; off <<= 1) m = fmaxf(m, __shfl_xor(m, off));
    float sum = 0.f;
    for (int j = sub; j < 100; j += 8) {
      float e = expf(s_lds[i][j] - m);
      s_lds[i][j] = e;
      sum += e;
    }
#pragma unroll
    for (int off = 1; off < 8; off <<= 1) sum += __shfl_xor(sum, off);
    float inv = 1.f / sum;
    for (int j = sub; j < 100; j += 8) s_lds[i][j] *= inv;
  }
  __syncthreads();
  {
    int ib = (t >> 4) * 2, db = (t & 15) * 4;
    float a0[4], a1[4];
#pragma unroll
    for (int dd = 0; dd < 4; ++dd) { a0[dd] = 0.f; a1[dd] = 0.f; }
    for (int j = 0; j < 100; ++j) {
      f32x4 vv = *(const f32x4*)&v_lds[j][db];
      float s0 = s_lds[ib][j], s1 = s_lds[ib + 1][j];
#pragma unroll
      for (int dd = 0; dd < 4; ++dd) {
        a0[dd] = fmaf(s0, vv[dd], a0[dd]);
        a1[dd] = fmaf(s1, vv[dd], a1[dd]);
      }
    }
#pragma unroll
    for (int dd = 0; dd < 4; ++dd) {
      f32x2 o; o[0] = a0[dd]; o[1] = a1[dd];
      *(f32x2*)&inner[(h * 64 + db + dd) * NP + i0 + ib] = o;
    }
  }
}

// ---------------- output projection 256x512 @ 512x1600 + bias --------------
// 800 blocks x 64 threads: 8 block-uniform couts (scalar w), 1 p per thread.
__global__ __launch_bounds__(64) void k_proj(
    const float* __restrict__ inner, const float* __restrict__ w,
    const float* __restrict__ bo, float* __restrict__ out) {
  int ot = blockIdx.x / 25;
  int pt = blockIdx.x - ot * 25;
  int o0 = ot * 8;
  int p = pt * 64 + threadIdx.x;
  const float* w0r = w + o0 * 512;   // block-uniform -> scalar loads
  float acc[8];
#pragma unroll
  for (int oo = 0; oo < 8; ++oo) acc[oo] = 0.f;
#pragma unroll 8
  for (int c = 0; c < 512; ++c) {
    float xv = inner[c * NP + p];
#pragma unroll
    for (int oo = 0; oo < 8; ++oo)
      acc[oo] = fmaf(w0r[oo * 512 + c], xv, acc[oo]);
  }
#pragma unroll
  for (int oo = 0; oo < 8; ++oo)
    out[(o0 + oo) * NP + p] = acc[oo] + bo[o0 + oo];
}

extern "C" void kernel_launch(void* const* d_in, const int* in_sizes, int n_in,
                              void* d_out, int out_size, void* d_ws, size_t ws_size,
                              hipStream_t stream) {
  int L = in_sizes[1] / (512 * 32);
  int l = L - 1;
  const float* x      = (const float*)d_in[0];
  const float* wq     = (const float*)d_in[1]  + (size_t)l * 512 * 32;
  const float* wk     = (const float*)d_in[2]  + (size_t)l * 512 * 32;
  const float* wv     = (const float*)d_in[3]  + (size_t)l * 512 * 32;
  const float* w_off1 = (const float*)d_in[4]  + (size_t)l * 64 * 36;
  const float* b_off1 = (const float*)d_in[5]  + (size_t)l * 64;
  const float* w_off2 = (const float*)d_in[6]  + (size_t)l * 2 * 64;
  const float* cpb_w0 = (const float*)d_in[7]  + (size_t)l * 64 * 2;
  const float* cpb_b0 = (const float*)d_in[8]  + (size_t)l * 64;
  const float* cpb_w1 = (const float*)d_in[9]  + (size_t)l * 64 * 64;
  const float* cpb_b1 = (const float*)d_in[10] + (size_t)l * 64;
  const float* cpb_w2 = (const float*)d_in[11] + (size_t)l * 64;
  const float* cpb_b2 = (const float*)d_in[12] + (size_t)l * 1;
  const float* w_out  = (const float*)d_in[13] + (size_t)l * 256 * 512;
  const float* b_out  = (const float*)d_in[14] + (size_t)l * 256;
  float* out = (float*)d_out;

  float* ws = (float*)d_ws;
  float* q_ws    = ws;               // 819200
  float* off1    = ws + 819200;      // 51200
  float* gkv     = ws + 870400;      // 1600
  float* k_ws    = ws + 872000;      // 51200
  float* v_ws    = ws + 923200;      // 51200
  float* bias_ws = ws + 974400;      // 1280000
  float* inner   = ws + 2254400;     // 819200   (end 3,073,600 f = 12.3 MB)

  k_conv1x1<<<320, 256, 0, stream>>>(x, wq, q_ws);
  k_off_dw<<<200, 256, 0, stream>>>(q_ws, w_off1, b_off1, off1);
  k_off_pw_kv<<<200, 256, 0, stream>>>(off1, w_off2, x, wk, wv,
                                       gkv, k_ws, v_ws);
  k_cpb_mfma<<<1250, 256, 0, stream>>>(gkv, cpb_w0, cpb_b0, cpb_w1, cpb_b1,
                                       cpb_w2, cpb_b2, bias_ws);
  k_attn<<<400, 256, 0, stream>>>(q_ws, k_ws, v_ws, bias_ws, inner);
  k_proj<<<800, 64, 0, stream>>>(inner, w_out, b_out, out);
}

// Round 4
// 140.734 us; speedup vs baseline: 2.4098x; 1.2377x over previous
//
#include <hip/hip_runtime.h>
#include <math.h>

// BEV deformable attention encoder, layer l = L-1 only.
// Round 4: k_cpb_mfma v2 — transposed pair ordering ((g,j) wave-uniform),
// precomputed signed-log coordinate tables (no per-pair transcendentals),
// __launch_bounds__(256,2) to kill register spilling (r3: VGPR 88 vs ~143
// live -> 143MB scratch FETCH). Bias stored transposed [gj][i]; attn reads
// it with f32x4 loads. Everything else unchanged from round 3.

#define NP 1600   // 40*40 query pixels
#define NJ 100    // 10*10 kv pixels

typedef __bf16 bf16x8 __attribute__((ext_vector_type(8)));
typedef float  f32x4  __attribute__((ext_vector_type(4)));
typedef float  f32x2  __attribute__((ext_vector_type(2)));

// ---------------- grouped 1x1 conv (q): 8 groups, cin/g=32, cout/g=64 ------
__global__ __launch_bounds__(256) void k_conv1x1(
    const float* __restrict__ x, const float* __restrict__ w,
    float* __restrict__ out) {
  int b = blockIdx.x;
  int g = b / 40;
  int r = b - g * 40;
  int oc = r / 5;
  int p0 = (r - oc * 5) * 320;
  int co0 = g * 64 + oc * 8;
  const float* xg = x + g * 32 * NP;
  const float* wr = w + co0 * 32;   // block-uniform -> scalar loads
  for (int p = p0 + threadIdx.x; p < p0 + 320; p += 256) {
    float acc[8];
#pragma unroll
    for (int o = 0; o < 8; ++o) acc[o] = 0.f;
#pragma unroll
    for (int ci = 0; ci < 32; ++ci) {
      float xv = xg[ci * NP + p];
#pragma unroll
      for (int o = 0; o < 8; ++o) acc[o] = fmaf(wr[o * 32 + ci], xv, acc[o]);
    }
#pragma unroll
    for (int o = 0; o < 8; ++o) out[(co0 + o) * NP + p] = acc[o];
  }
}

// ------------- offset depthwise 6x6 s4 pad1 + bias + exact GELU ------------
__global__ __launch_bounds__(256) void k_off_dw(
    const float* __restrict__ q, const float* __restrict__ w1,
    const float* __restrict__ b1, float* __restrict__ off1) {
  int idx = blockIdx.x * 256 + threadIdx.x;   // 51200 exactly
  int j = idx % 100;
  int d = (idx / 100) & 63;
  int bg = idx / 6400;
  int oy = j / 10, ox = j - (j / 10) * 10;
  float acc = b1[d];
  const float* qc = q + (bg * 64 + d) * NP;
#pragma unroll
  for (int ky = 0; ky < 6; ++ky) {
    int iy = oy * 4 - 1 + ky;
    if (iy < 0 || iy >= 40) continue;
#pragma unroll
    for (int kx = 0; kx < 6; ++kx) {
      int ix = ox * 4 - 1 + kx;
      if (ix < 0 || ix >= 40) continue;
      acc = fmaf(w1[d * 36 + ky * 6 + kx], qc[iy * 40 + ix], acc);
    }
  }
  off1[idx] = 0.5f * acc * (1.0f + erff(acc * 0.70710678118654752440f));
}

// ------- fused: offset 1x1 + tanh*4 + grid + sample + k/v conv + tables ----
// One WAVE per (g,j): 800 waves = 200 blocks x 256.
__global__ __launch_bounds__(256) void k_off_pw_kv(
    const float* __restrict__ off1, const float* __restrict__ w2,
    const float* __restrict__ x, const float* __restrict__ wk,
    const float* __restrict__ wv, float* __restrict__ kout,
    float* __restrict__ vout, float* __restrict__ su_tab,
    float* __restrict__ sv_tab) {
  int lane = threadIdx.x & 63;
  int wid = blockIdx.x * 4 + (threadIdx.x >> 6);
  int g = wid / 100;
  int j = wid - g * 100;
  const float* wkr = wk + (g * 64 + lane) * 32;
  const float* wvr = wv + (g * 64 + lane) * 32;
  float wkreg[32], wvreg[32];
#pragma unroll
  for (int q4 = 0; q4 < 8; ++q4) {
    f32x4 a = *(const f32x4*)(wkr + q4 * 4);
    f32x4 b = *(const f32x4*)(wvr + q4 * 4);
#pragma unroll
    for (int e = 0; e < 4; ++e) { wkreg[q4 * 4 + e] = a[e]; wvreg[q4 * 4 + e] = b[e]; }
  }
  // pointwise offset conv + tanh*4
  float o = off1[(g * 64 + lane) * 100 + j];
  float px = w2[lane] * o, py = w2[64 + lane] * o;
#pragma unroll
  for (int m = 1; m < 64; m <<= 1) {
    px += __shfl_xor(px, m);
    py += __shfl_xor(py, m);
  }
  float ax = tanhf(px) * 4.f;
  float ay = tanhf(py) * 4.f;
  float vx = (float)(j - (j / 10) * 10) + ax;
  float vy = (float)(j / 10) + ay;
  float g0 = 2.f * vx / 9.f - 1.f;
  float g1 = 2.f * vy / 9.f - 1.f;
  // CPB signed-log coordinate tables: one entry per (gj, coord 0..39)
  if (lane < 40) {
    float qc = (float)lane * (2.f / 39.f) - 1.f;
    float u = qc - g0;
    float vv = qc - g1;
    su_tab[wid * 40 + lane] = copysignf(log1pf(fabsf(u)), u);
    sv_tab[wid * 40 + lane] = copysignf(log1pf(fabsf(vv)), vv);
  }
  // bilinear sample (uniform weights; lanes<32 gather), then k/v conv
  float gx = ((g0 + 1.f) * 40.f - 1.f) * 0.5f;
  float gy = ((g1 + 1.f) * 40.f - 1.f) * 0.5f;
  float x0f = floorf(gx), y0f = floorf(gy);
  float wx = gx - x0f, wy = gy - y0f;
  bool mx0 = (x0f >= 0.f) && (x0f <= 39.f);
  bool mx1 = (x0f + 1.f >= 0.f) && (x0f + 1.f <= 39.f);
  bool my0 = (y0f >= 0.f) && (y0f <= 39.f);
  bool my1 = (y0f + 1.f >= 0.f) && (y0f + 1.f <= 39.f);
  int ix0 = (int)fminf(fmaxf(x0f, 0.f), 39.f);
  int ix1 = (int)fminf(fmaxf(x0f + 1.f, 0.f), 39.f);
  int iy0 = (int)fminf(fmaxf(y0f, 0.f), 39.f);
  int iy1 = (int)fminf(fmaxf(y0f + 1.f, 0.f), 39.f);
  float w00 = (1.f - wx) * (1.f - wy) * ((mx0 && my0) ? 1.f : 0.f);
  float w10 = wx * (1.f - wy) * ((mx1 && my0) ? 1.f : 0.f);
  float w01 = (1.f - wx) * wy * ((mx0 && my1) ? 1.f : 0.f);
  float w11 = wx * wy * ((mx1 && my1) ? 1.f : 0.f);
  int b00 = iy0 * 40 + ix0, b10 = iy0 * 40 + ix1;
  int b01 = iy1 * 40 + ix0, b11 = iy1 * 40 + ix1;
  float kvc = 0.f;
  if (lane < 32) {
    const float* xc = x + (g * 32 + lane) * NP;
    kvc = w00 * xc[b00] + w10 * xc[b10] + w01 * xc[b01] + w11 * xc[b11];
  }
  float kacc = 0.f, vacc = 0.f;
#pragma unroll
  for (int c = 0; c < 32; ++c) {
    float kvb = __shfl(kvc, c);
    kacc = fmaf(wkreg[c], kvb, kacc);
    vacc = fmaf(wvreg[c], kvb, vacc);
  }
  kout[(g * 64 + lane) * 100 + j] = kacc;
  vout[(g * 64 + lane) * 100 + j] = vacc;
}

// ---------------- CPB bias MLP v2: transposed ordering, split-bf16 MFMA ----
// Column gj = g*100+j (wave-uniform); tile = 16 consecutive i; 100 tiles per
// column, 5 waves/column x 20 tiles. bias_t layout [gj][i] (transposed).
__global__ __launch_bounds__(256, 2) void k_cpb_mfma(
    const float* __restrict__ su_tab, const float* __restrict__ sv_tab,
    const float* __restrict__ w0, const float* __restrict__ b0,
    const float* __restrict__ w1, const float* __restrict__ b1v,
    const float* __restrict__ w2, const float* __restrict__ b2,
    float* __restrict__ bias_t) {
  int lane = threadIdx.x & 63;
  int wid = blockIdx.x * 4 + (threadIdx.x >> 6);   // 4000 waves
  int gj = wid / 5;
  int it0 = (wid - gj * 5) * 20;
  int row = lane & 15;
  int kgrp = lane >> 4;

  // B fragments: B[k][c] = w1[c][k]; hi/lo bf16 split
  bf16x8 Bhi[4][2], Blo[4][2];
#pragma unroll
  for (int ct = 0; ct < 4; ++ct)
#pragma unroll
    for (int s = 0; s < 2; ++s)
#pragma unroll
      for (int e = 0; e < 8; ++e) {
        float wvv = w1[(ct * 16 + row) * 64 + s * 32 + kgrp * 8 + e];
        __bf16 h = (__bf16)wvv;
        Bhi[ct][s][e] = h;
        Blo[ct][s][e] = (__bf16)(wvv - (float)h);
      }
  float w0x[2][8], w0y[2][8], b0v[2][8];
#pragma unroll
  for (int s = 0; s < 2; ++s)
#pragma unroll
    for (int e = 0; e < 8; ++e) {
      int kk = s * 32 + kgrp * 8 + e;
      w0x[s][e] = w0[2 * kk];
      w0y[s][e] = w0[2 * kk + 1];
      b0v[s][e] = b0[kk];
    }
  float b1c[4], w2c[4];
#pragma unroll
  for (int ct = 0; ct < 4; ++ct) {
    b1c[ct] = b1v[ct * 16 + row];
    w2c[ct] = w2[ct * 16 + row];
  }
  float bb = b2[0];
  const float* su_p = su_tab + gj * 40;
  const float* sv_p = sv_tab + gj * 40;
  float* outp = bias_t + (size_t)gj * 1600;

  for (int it = it0; it < it0 + 20; ++it) {
    int i = it * 16 + row;
    int iy = i / 40;
    int ix = i - iy * 40;
    float su = su_p[ix];
    float sv = sv_p[iy];

    f32x4 acc[4];
#pragma unroll
    for (int ct = 0; ct < 4; ++ct) {
      acc[ct][0] = 0.f; acc[ct][1] = 0.f; acc[ct][2] = 0.f; acc[ct][3] = 0.f;
    }
#pragma unroll
    for (int s = 0; s < 2; ++s) {
      bf16x8 Ahi, Alo;
#pragma unroll
      for (int e = 0; e < 8; ++e) {
        float h0 = fmaf(w0x[s][e], su, fmaf(w0y[s][e], sv, b0v[s][e]));
        h0 = fmaxf(h0, 0.f);
        __bf16 hh = (__bf16)h0;
        Ahi[e] = hh;
        Alo[e] = (__bf16)(h0 - (float)hh);
      }
#pragma unroll
      for (int ct = 0; ct < 4; ++ct) {
        acc[ct] = __builtin_amdgcn_mfma_f32_16x16x32_bf16(Ahi, Bhi[ct][s], acc[ct], 0, 0, 0);
        acc[ct] = __builtin_amdgcn_mfma_f32_16x16x32_bf16(Ahi, Blo[ct][s], acc[ct], 0, 0, 0);
        acc[ct] = __builtin_amdgcn_mfma_f32_16x16x32_bf16(Alo, Bhi[ct][s], acc[ct], 0, 0, 0);
      }
    }
    // epilogue: s2 = acc + b1; out_row = sum_c w2[c]*relu(s2[c]) + b2
    float part[4];
#pragma unroll
    for (int ri = 0; ri < 4; ++ri) {
      float s2 = 0.f;
#pragma unroll
      for (int ct = 0; ct < 4; ++ct) {
        float val = acc[ct][ri] + b1c[ct];
        s2 = fmaf(w2c[ct], fmaxf(val, 0.f), s2);
      }
      part[ri] = s2;
    }
#pragma unroll
    for (int m = 1; m < 16; m <<= 1) {
#pragma unroll
      for (int ri = 0; ri < 4; ++ri) part[ri] += __shfl_xor(part[ri], m);
    }
    if (row == 0) {
      f32x4 o;
      o[0] = part[0] + bb; o[1] = part[1] + bb;
      o[2] = part[2] + bb; o[3] = part[3] + bb;
      *(f32x4*)(outp + it * 16 + kgrp * 4) = o;
    }
  }
}

// ---------------- fused attention, register-tiled (bias read transposed) ---
__global__ __launch_bounds__(256) void k_attn(
    const float* __restrict__ q, const float* __restrict__ k,
    const float* __restrict__ v, const float* __restrict__ bias_t,
    float* __restrict__ inner) {
  __shared__ float k_lds[64][104];
  __shared__ float v_lds[100][68];
  __shared__ float q_lds[64][36];
  __shared__ float s_lds[32][100];
  int h = blockIdx.x / 50;
  int i0 = (blockIdx.x % 50) * 32;
  int t = threadIdx.x;
  for (int idx = t; idx < 6400; idx += 256) {
    int d = idx / 100, j = idx - (idx / 100) * 100;
    k_lds[d][j] = k[(h * 64 + d) * 100 + j];
    v_lds[j][d] = v[(h * 64 + d) * 100 + j];
  }
  for (int idx = t; idx < 2048; idx += 256) {
    int d = idx >> 5, i = idx & 31;
    q_lds[d][i] = q[(h * 64 + d) * NP + i0 + i] * 0.125f;
  }
  __syncthreads();
  if (t < 200) {
    int ib = (t / 25) * 4, jb = (t % 25) * 4;
    float a[4][4];
#pragma unroll
    for (int ii = 0; ii < 4; ++ii)
#pragma unroll
      for (int jj = 0; jj < 4; ++jj) a[ii][jj] = 0.f;
    for (int d = 0; d < 64; ++d) {
      f32x4 qv = *(const f32x4*)&q_lds[d][ib];
      f32x4 kv4 = *(const f32x4*)&k_lds[d][jb];
#pragma unroll
      for (int ii = 0; ii < 4; ++ii)
#pragma unroll
        for (int jj = 0; jj < 4; ++jj)
          a[ii][jj] = fmaf(qv[ii], kv4[jj], a[ii][jj]);
    }
    const float* bcol = bias_t + (size_t)h * 100 * 1600;
#pragma unroll
    for (int jj = 0; jj < 4; ++jj) {
      f32x4 bv = *(const f32x4*)(bcol + (size_t)(jb + jj) * 1600 + i0 + ib);
#pragma unroll
      for (int ii = 0; ii < 4; ++ii)
        s_lds[ib + ii][jb + jj] = a[ii][jj] + bv[ii];
    }
  }
  __syncthreads();
  {
    int i = t >> 3, sub = t & 7;
    float m = -1e30f;
    for (int j = sub; j < 100; j += 8) m = fmaxf(m, s_lds[i][j]);
#pragma unroll
    for (int off = 1; off < 8; off <<= 1) m = fmaxf(m, __shfl_xor(m, off));
    float sum = 0.f;
    for (int j = sub; j < 100; j += 8) {
      float e = expf(s_lds[i][j] - m);
      s_lds[i][j] = e;
      sum += e;
    }
#pragma unroll
    for (int off = 1; off < 8; off <<= 1) sum += __shfl_xor(sum, off);
    float inv = 1.f / sum;
    for (int j = sub; j < 100; j += 8) s_lds[i][j] *= inv;
  }
  __syncthreads();
  {
    int ib = (t >> 4) * 2, db = (t & 15) * 4;
    float a0[4], a1[4];
#pragma unroll
    for (int dd = 0; dd < 4; ++dd) { a0[dd] = 0.f; a1[dd] = 0.f; }
    for (int j = 0; j < 100; ++j) {
      f32x4 vv = *(const f32x4*)&v_lds[j][db];
      float s0 = s_lds[ib][j], s1 = s_lds[ib + 1][j];
#pragma unroll
      for (int dd = 0; dd < 4; ++dd) {
        a0[dd] = fmaf(s0, vv[dd], a0[dd]);
        a1[dd] = fmaf(s1, vv[dd], a1[dd]);
      }
    }
#pragma unroll
    for (int dd = 0; dd < 4; ++dd) {
      f32x2 o; o[0] = a0[dd]; o[1] = a1[dd];
      *(f32x2*)&inner[(h * 64 + db + dd) * NP + i0 + ib] = o;
    }
  }
}

// ---------------- output projection 256x512 @ 512x1600 + bias --------------
__global__ __launch_bounds__(64) void k_proj(
    const float* __restrict__ inner, const float* __restrict__ w,
    const float* __restrict__ bo, float* __restrict__ out) {
  int ot = blockIdx.x / 25;
  int pt = blockIdx.x - ot * 25;
  int o0 = ot * 8;
  int p = pt * 64 + threadIdx.x;
  const float* w0r = w + o0 * 512;   // block-uniform -> scalar loads
  float acc[8];
#pragma unroll
  for (int oo = 0; oo < 8; ++oo) acc[oo] = 0.f;
#pragma unroll 8
  for (int c = 0; c < 512; ++c) {
    float xv = inner[c * NP + p];
#pragma unroll
    for (int oo = 0; oo < 8; ++oo)
      acc[oo] = fmaf(w0r[oo * 512 + c], xv, acc[oo]);
  }
#pragma unroll
  for (int oo = 0; oo < 8; ++oo)
    out[(o0 + oo) * NP + p] = acc[oo] + bo[o0 + oo];
}

extern "C" void kernel_launch(void* const* d_in, const int* in_sizes, int n_in,
                              void* d_out, int out_size, void* d_ws, size_t ws_size,
                              hipStream_t stream) {
  int L = in_sizes[1] / (512 * 32);
  int l = L - 1;
  const float* x      = (const float*)d_in[0];
  const float* wq     = (const float*)d_in[1]  + (size_t)l * 512 * 32;
  const float* wk     = (const float*)d_in[2]  + (size_t)l * 512 * 32;
  const float* wv     = (const float*)d_in[3]  + (size_t)l * 512 * 32;
  const float* w_off1 = (const float*)d_in[4]  + (size_t)l * 64 * 36;
  const float* b_off1 = (const float*)d_in[5]  + (size_t)l * 64;
  const float* w_off2 = (const float*)d_in[6]  + (size_t)l * 2 * 64;
  const float* cpb_w0 = (const float*)d_in[7]  + (size_t)l * 64 * 2;
  const float* cpb_b0 = (const float*)d_in[8]  + (size_t)l * 64;
  const float* cpb_w1 = (const float*)d_in[9]  + (size_t)l * 64 * 64;
  const float* cpb_b1 = (const float*)d_in[10] + (size_t)l * 64;
  const float* cpb_w2 = (const float*)d_in[11] + (size_t)l * 64;
  const float* cpb_b2 = (const float*)d_in[12] + (size_t)l * 1;
  const float* w_out  = (const float*)d_in[13] + (size_t)l * 256 * 512;
  const float* b_out  = (const float*)d_in[14] + (size_t)l * 256;
  float* out = (float*)d_out;

  float* ws = (float*)d_ws;
  float* q_ws    = ws;               // 819200
  float* off1    = ws + 819200;      // 51200
  float* k_ws    = ws + 870400;      // 51200
  float* v_ws    = ws + 921600;      // 51200
  float* bias_t  = ws + 972800;      // 1280000 (transposed [gj][i])
  float* inner   = ws + 2252800;     // 819200  (end 3,072,000 f = 12.29 MB)
  // su/sv tables (800*40 each) alias inner's head: written by k_off_pw_kv,
  // read by k_cpb_mfma, dead before k_attn overwrites inner. Sequential
  // same-stream launches make this deterministic.
  float* su_tab  = inner;            // 32000
  float* sv_tab  = inner + 32000;    // 32000

  k_conv1x1<<<320, 256, 0, stream>>>(x, wq, q_ws);
  k_off_dw<<<200, 256, 0, stream>>>(q_ws, w_off1, b_off1, off1);
  k_off_pw_kv<<<200, 256, 0, stream>>>(off1, w_off2, x, wk, wv,
                                       k_ws, v_ws, su_tab, sv_tab);
  k_cpb_mfma<<<1000, 256, 0, stream>>>(su_tab, sv_tab, cpb_w0, cpb_b0,
                                       cpb_w1, cpb_b1, cpb_w2, cpb_b2, bias_t);
  k_attn<<<400, 256, 0, stream>>>(q_ws, k_ws, v_ws, bias_t, inner);
  k_proj<<<800, 64, 0, stream>>>(inner, w_out, b_out, out);
}